// Round 5
// baseline (90.053 us; speedup 1.0000x reference)
//
#include <hip/hip_runtime.h>
#include <math.h>

#define M_PTS    2048
#define N_VOX    65536
#define VPT      8                      // voxels per lane (k1)
#define VGRP     512                    // voxels per group (64 lanes * VPT)
#define NGRP     (N_VOX / VGRP)         // 128 voxel groups
#define HALF_PTS 1024                   // points per M-half
#define K1_BLK   256                    // 128 groups x 2 M-halves -> 1 block per CU
#define K1_WAVES 16
#define K1_CHUNK (HALF_PTS / K1_WAVES)  // 64 points per wave
#define K2_BLK   (N_VOX / 256)          // 256 blocks x 256 threads

// ws layout (floats): pm[2][N_VOX] at 0; partial[256*4] at 2*N_VOX; cnt (u32) at 2*N_VOX+1024.
// cnt is initialized by k_min (stream order: k_min fully completes before k_occ_final
// starts), so the poisoned workspace never feeds the ticket counter.

// ---------------- k1: per-(voxel-group, M-half) min of t = h - c.p  [R2-proven exact] ----------------
__global__ __launch_bounds__(1024) void k_min(const float* __restrict__ quat,
                                              const float* __restrict__ tran,
                                              const float* __restrict__ model,
                                              const float* __restrict__ view,
                                              const float* __restrict__ centers,
                                              float* __restrict__ pm,
                                              unsigned* __restrict__ cnt) {
    __shared__ float4 sp[HALF_PTS];              // (x,y,z)/RES, h=0.5*|p/RES|^2 -> 16 KB
    __shared__ float  pmin[K1_WAVES][VGRP];      // -> 32 KB

    const int tid  = threadIdx.x;
    const int lane = tid & 63;
    const int wave = tid >> 6;
    const int g    = blockIdx.x >> 1;            // voxel group
    const int hb   = blockIdx.x & 1;             // M-half

    // seed the k2 ticket counter (visible to k2 via stream order + coherence point)
    if (blockIdx.x == 0 && tid == 0)
        __hip_atomic_store(cnt, 0u, __ATOMIC_RELAXED, __HIP_MEMORY_SCOPE_AGENT);

    // ---- issue center loads early (voxel id = g*VGRP + k*64 + lane: coalesced) ----
    float nx[VPT], ny[VPT], nz[VPT], mm[VPT];
    #pragma unroll
    for (int k = 0; k < VPT; k++) {
        int gv = g * VGRP + k * 64 + lane;
        nx[k] = -centers[3*gv + 0] * 2.0f;       // -(c/RES)
        ny[k] = -centers[3*gv + 1] * 2.0f;
        nz[k] = -centers[3*gv + 2] * 2.0f;
        mm[k] = 1e30f;
    }

    // ---- per-block uniform prep: W = inv(view) * quat_matrix ----
    float W[16];
    {
        float q0 = quat[0], q1 = quat[1], q2 = quat[2], q3 = quat[3];
        float nq = q0*q0 + q1*q1 + q2*q2 + q3*q3;
        float s = sqrtf(2.0f / nq);
        q0 *= s; q1 *= s; q2 *= s; q3 *= s;
        float E[16];
        E[0]  = 1.0f - q2*q2 - q3*q3; E[1]  = q1*q2 - q3*q0;        E[2]  = q1*q3 + q2*q0;        E[3]  = tran[0];
        E[4]  = q1*q2 + q3*q0;        E[5]  = 1.0f - q1*q1 - q3*q3; E[6]  = q2*q3 - q1*q0;        E[7]  = tran[1];
        E[8]  = q1*q3 - q2*q0;        E[9]  = q2*q3 + q1*q0;        E[10] = 1.0f - q1*q1 - q2*q2; E[11] = tran[2];
        E[12] = 0.0f; E[13] = 0.0f; E[14] = 0.0f; E[15] = 1.0f;

        float m[16], inv[16];
        #pragma unroll
        for (int i = 0; i < 16; i++) m[i] = view[i];

        inv[0]  =  m[5]*m[10]*m[15] - m[5]*m[11]*m[14] - m[9]*m[6]*m[15] + m[9]*m[7]*m[14] + m[13]*m[6]*m[11] - m[13]*m[7]*m[10];
        inv[4]  = -m[4]*m[10]*m[15] + m[4]*m[11]*m[14] + m[8]*m[6]*m[15] - m[8]*m[7]*m[14] - m[12]*m[6]*m[11] + m[12]*m[7]*m[10];
        inv[8]  =  m[4]*m[9]*m[15]  - m[4]*m[11]*m[13] - m[8]*m[5]*m[15] + m[8]*m[7]*m[13] + m[12]*m[5]*m[11] - m[12]*m[7]*m[9];
        inv[12] = -m[4]*m[9]*m[14]  + m[4]*m[10]*m[13] + m[8]*m[5]*m[14] - m[8]*m[6]*m[13] - m[12]*m[5]*m[10] + m[12]*m[6]*m[9];
        inv[1]  = -m[1]*m[10]*m[15] + m[1]*m[11]*m[14] + m[9]*m[2]*m[15] - m[9]*m[3]*m[14] - m[13]*m[2]*m[11] + m[13]*m[3]*m[10];
        inv[5]  =  m[0]*m[10]*m[15] - m[0]*m[11]*m[14] - m[8]*m[2]*m[15] + m[8]*m[3]*m[14] + m[12]*m[2]*m[11] - m[12]*m[3]*m[10];
        inv[9]  = -m[0]*m[9]*m[15]  + m[0]*m[11]*m[13] + m[8]*m[1]*m[15] - m[8]*m[3]*m[13] - m[12]*m[1]*m[11] + m[12]*m[3]*m[9];
        inv[13] =  m[0]*m[9]*m[14]  - m[0]*m[10]*m[13] - m[8]*m[1]*m[14] + m[8]*m[2]*m[13] + m[12]*m[1]*m[10] - m[12]*m[2]*m[9];
        inv[2]  =  m[1]*m[6]*m[15]  - m[1]*m[7]*m[14]  - m[5]*m[2]*m[15] + m[5]*m[3]*m[14] + m[13]*m[2]*m[7]  - m[13]*m[3]*m[6];
        inv[6]  = -m[0]*m[6]*m[15]  + m[0]*m[7]*m[14]  + m[4]*m[2]*m[15] - m[4]*m[3]*m[14] - m[12]*m[2]*m[7]  + m[12]*m[3]*m[6];
        inv[10] =  m[0]*m[5]*m[15]  - m[0]*m[7]*m[13]  - m[4]*m[1]*m[15] + m[4]*m[3]*m[13] + m[12]*m[1]*m[7]  - m[12]*m[3]*m[5];
        inv[14] = -m[0]*m[5]*m[14]  + m[0]*m[6]*m[13]  + m[4]*m[1]*m[14] - m[4]*m[2]*m[13] - m[12]*m[1]*m[6]  + m[12]*m[2]*m[5];
        inv[3]  = -m[1]*m[6]*m[11]  + m[1]*m[7]*m[10]  + m[5]*m[2]*m[11] - m[5]*m[3]*m[10] - m[9]*m[2]*m[7]   + m[9]*m[3]*m[6];
        inv[7]  =  m[0]*m[6]*m[11]  - m[0]*m[7]*m[10]  - m[4]*m[2]*m[11] + m[4]*m[3]*m[10] + m[8]*m[2]*m[7]   - m[8]*m[3]*m[6];
        inv[11] = -m[0]*m[5]*m[11]  + m[0]*m[7]*m[9]   + m[4]*m[1]*m[11] - m[4]*m[3]*m[9]  - m[8]*m[1]*m[7]   + m[8]*m[3]*m[5];
        inv[15] =  m[0]*m[5]*m[10]  - m[0]*m[6]*m[9]   - m[4]*m[1]*m[10] + m[4]*m[2]*m[9]  + m[8]*m[1]*m[6]   - m[8]*m[2]*m[5];

        float det = m[0]*inv[0] + m[1]*inv[4] + m[2]*inv[8] + m[3]*inv[12];
        float rdet = 1.0f / det;

        #pragma unroll
        for (int r = 0; r < 4; r++) {
            #pragma unroll
            for (int c = 0; c < 4; c++) {
                float a = 0.0f;
                #pragma unroll
                for (int k = 0; k < 4; k++) a += inv[4*r+k] * rdet * E[4*k+c];
                W[4*r+c] = a;
            }
        }
    }

    // ---- transform own chunk into LDS (1 pt/thread; wave w writes exactly sp[w*64..+64)) ----
    // No barrier needed: each wave later reads only its own chunk; DS ops are in-order per wave.
    {
        const int ip = hb * HALF_PTS + tid;          // global point id
        float x = model[3*ip + 0];
        float y = model[3*ip + 1];
        float z = model[3*ip + 2];
        float X  = W[0]*x + W[1]*y + W[2]*z  + W[3];
        float Y  = W[4]*x + W[5]*y + W[6]*z  + W[7];
        float Z  = W[8]*x + W[9]*y + W[10]*z + W[11];
        float Wd = W[12]*x + W[13]*y + W[14]*z + W[15];
        float rw = 2.0f / Wd;                        // (1/w) * (1/RES)
        float px = X * rw, py = Y * rw, pz = Z * rw;
        float hh = 0.5f * (px*px + py*py + pz*pz);
        sp[tid] = make_float4(px, py, pz, hh);
    }

    // ---- main: wave's 64-pt chunk vs lane's 8 voxels; paired points -> v_min3 ----
    const float4* base = sp + wave * K1_CHUNK;
    #pragma unroll 4
    for (int j = 0; j < K1_CHUNK; j += 2) {
        float4 p0 = base[j];                         // wave-uniform addr -> LDS broadcast
        float4 p1 = base[j + 1];
        #pragma unroll
        for (int k = 0; k < VPT; k++) {
            float t0 = fmaf(nx[k], p0.x, fmaf(ny[k], p0.y, fmaf(nz[k], p0.z, p0.w)));
            float t1 = fmaf(nx[k], p1.x, fmaf(ny[k], p1.y, fmaf(nz[k], p1.z, p1.w)));
            mm[k] = fminf(mm[k], fminf(t0, t1));
        }
    }
    #pragma unroll
    for (int k = 0; k < VPT; k++)
        pmin[wave][k * 64 + lane] = mm[k];           // consecutive lanes -> conflict-free
    __syncthreads();

    // ---- combine 16 waves, write this half's per-voxel t-min to global ----
    if (tid < VGRP) {
        float m = 1e30f;
        #pragma unroll
        for (int c = 0; c < K1_WAVES; c++)
            m = fminf(m, pmin[c][tid]);
        pm[hb * N_VOX + g * VGRP + tid] = m;
    }
}

// ---------------- k2: combine halves + occupancy + partials + last-block final fold ----------------
// occ math & partial tree verbatim from R2's k_occ; fold verbatim from k_final;
// cross-block protocol = R4-proven relaxed-atomic scheme (no fences except one acquire).
__global__ __launch_bounds__(256) void k_occ_final(const float* __restrict__ centers,
                                                   const float* __restrict__ freev,
                                                   const float* __restrict__ occ_other,
                                                   const float* __restrict__ masks,
                                                   const float* __restrict__ pm,
                                                   float* __restrict__ partial,
                                                   unsigned* __restrict__ cnt,
                                                   float* __restrict__ out) {
    __shared__ float sred[16];
    __shared__ int   is_last;
    const int tid  = threadIdx.x;
    const int lane = tid & 63;
    const int wave = tid >> 6;
    const int v    = blockIdx.x * 256 + tid;

    float m  = fminf(pm[v], pm[N_VOX + v]);
    float cx = centers[3*v + 0] * 2.0f;
    float cy = centers[3*v + 1] * 2.0f;
    float cz = centers[3*v + 2] * 2.0f;
    float c2 = cx*cx + cy*cy + cz*cz;
    float d2 = fmaf(2.0f, m, c2);
    float dmin = fminf(sqrtf(fmaxf(d2, 0.0f)), 0.25f);   // clamp at RES/2
    float occ  = fmaxf(1.0f - 4.0f * dmin, 0.0f);

    float mk = masks[v];
    float v0 = occ;
    float v1 = (freev[v] + occ_other[v]) * occ;
    float v2 = mk * occ;
    float v3 = mk;

    #pragma unroll
    for (int off = 32; off > 0; off >>= 1) {
        v0 += __shfl_down(v0, off);
        v1 += __shfl_down(v1, off);
        v2 += __shfl_down(v2, off);
        v3 += __shfl_down(v3, off);
    }
    if (lane == 0) {
        sred[wave*4 + 0] = v0;
        sred[wave*4 + 1] = v1;
        sred[wave*4 + 2] = v2;
        sred[wave*4 + 3] = v3;
    }
    __syncthreads();

    // publish this block's 4 partials (relaxed agent atomics -> coherence point)
    if (tid < 4) {
        float s = sred[tid] + sred[4 + tid] + sred[8 + tid] + sred[12 + tid];
        __hip_atomic_store(&partial[blockIdx.x * 4 + tid], s,
                           __ATOMIC_RELAXED, __HIP_MEMORY_SCOPE_AGENT);
    }
    __syncthreads();                       // drains vmcnt(0): partials globally visible
    if (tid == 0) {
        unsigned old = __hip_atomic_fetch_add(cnt, 1u, __ATOMIC_RELAXED,
                                              __HIP_MEMORY_SCOPE_AGENT);
        is_last = (old == (unsigned)(K2_BLK - 1));
    }
    __syncthreads();

    if (is_last) {
        // One-time acquire: compiler reorder guard + this-CU L1 invalidate.
        __builtin_amdgcn_fence(__ATOMIC_ACQUIRE, "agent");
        float w0, w1, w2, w3;
        w0 = __hip_atomic_load(&partial[tid*4 + 0], __ATOMIC_RELAXED, __HIP_MEMORY_SCOPE_AGENT);
        w1 = __hip_atomic_load(&partial[tid*4 + 1], __ATOMIC_RELAXED, __HIP_MEMORY_SCOPE_AGENT);
        w2 = __hip_atomic_load(&partial[tid*4 + 2], __ATOMIC_RELAXED, __HIP_MEMORY_SCOPE_AGENT);
        w3 = __hip_atomic_load(&partial[tid*4 + 3], __ATOMIC_RELAXED, __HIP_MEMORY_SCOPE_AGENT);
        #pragma unroll
        for (int off = 32; off > 0; off >>= 1) {
            w0 += __shfl_down(w0, off);
            w1 += __shfl_down(w1, off);
            w2 += __shfl_down(w2, off);
            w3 += __shfl_down(w3, off);
        }
        __syncthreads();                   // sred reuse: prior phase fully consumed
        if (lane == 0) {
            sred[wave*4 + 0] = w0;
            sred[wave*4 + 1] = w1;
            sred[wave*4 + 2] = w2;
            sred[wave*4 + 3] = w3;
        }
        __syncthreads();
        if (tid == 0) {
            float ps = sred[0] + sred[4] + sred[8]  + sred[12];
            float fo = sred[1] + sred[5] + sred[9]  + sred[13];
            float mo = sred[2] + sred[6] + sred[10] + sred[14];
            float ms = sred[3] + sred[7] + sred[11] + sred[15];
            float t1 = (ps > 0.0f) ? (fo / ps) : 0.0f;
            float t2 = (ms > 0.0f) ? (mo / ms) : 0.0f;
            out[0] = t1 - t2;
        }
    }
}

extern "C" void kernel_launch(void* const* d_in, const int* in_sizes, int n_in,
                              void* d_out, int out_size, void* d_ws, size_t ws_size,
                              hipStream_t stream) {
    const float* quat      = (const float*)d_in[0];
    const float* tran      = (const float*)d_in[1];
    const float* model     = (const float*)d_in[2];
    const float* view      = (const float*)d_in[3];
    const float* centers   = (const float*)d_in[4];
    const float* freev     = (const float*)d_in[5];
    const float* occ_other = (const float*)d_in[6];
    const float* masks     = (const float*)d_in[7];
    float* out     = (float*)d_out;
    float* pm      = (float*)d_ws;              // 2*N_VOX floats
    float* partial = pm + 2 * N_VOX;            // 1024 floats
    unsigned* cnt  = (unsigned*)(partial + 1024);

    k_min<<<K1_BLK, 1024, 0, stream>>>(quat, tran, model, view, centers, pm, cnt);
    k_occ_final<<<K2_BLK, 256, 0, stream>>>(centers, freev, occ_other, masks, pm,
                                            partial, cnt, out);
}

// Round 6
// 86.647 us; speedup vs baseline: 1.0393x; 1.0393x over previous
//
#include <hip/hip_runtime.h>
#include <math.h>

#define M_PTS   2048
#define N_VOX   65536
#define VPT     4                    // voxels per lane
#define VPB     256                  // voxels per block (64 lanes * VPT)
#define NBLK    (N_VOX / VPB)        // 256 blocks (1 per CU)
#define NWAVES  16                   // 1024-thread blocks
#define CHUNK   (M_PTS / NWAVES)     // 128 points per wave

// ws layout (floats): [0, 1024) per-block partials {pred_sum, fo_sum, mask_occ_sum, mask_sum} x 256
//
// Session record (R0-R5): 2-dispatch stream-ordered is the proven optimum on this
// harness. Cooperative grid-sync = +98us (launch+fence tax); in-kernel flag/ticket
// sync = +4..9us (spin tail + cache-maintenance > one dispatch gap); 3-dispatch
// M-split = +4us (extra gap + cross-XCD pm re-read). Kernel share ~15us of ~84us
// window; the rest is the harness's fixed 256MiB ws poison fill (~40us) + resets.

__global__ __launch_bounds__(1024) void k_fused(const float* __restrict__ quat,
                                                const float* __restrict__ tran,
                                                const float* __restrict__ model,
                                                const float* __restrict__ view,
                                                const float* __restrict__ centers,
                                                const float* __restrict__ freev,
                                                const float* __restrict__ occ_other,
                                                const float* __restrict__ masks,
                                                float* __restrict__ partial) {
    __shared__ float4 sp[M_PTS];             // (x,y,z)/RES, h = 0.5*|p/RES|^2  -> 32 KB
    __shared__ float  pmin[NWAVES * VPB];    // [wave][local voxel]             -> 16 KB
    __shared__ float  sred[16];              // cross-wave sum combine

    const int tid  = threadIdx.x;
    const int lane = tid & 63;
    const int wave = tid >> 6;

    // ---- issue center loads early (depend on nothing; overlap the W computation) ----
    const int vbase = blockIdx.x * VPB + lane * VPT;
    float nx[VPT], ny[VPT], nz[VPT], mm[VPT];
    #pragma unroll
    for (int k = 0; k < VPT; k++) {
        int g = vbase + k;
        nx[k] = -centers[3*g + 0] * 2.0f;   // -(c/RES)
        ny[k] = -centers[3*g + 1] * 2.0f;
        nz[k] = -centers[3*g + 2] * 2.0f;
        mm[k] = 1e30f;
    }

    // ---- per-block uniform prep: W = inv(view) * quat_matrix (redundant on all threads) ----
    float W[16];
    {
        float q0 = quat[0], q1 = quat[1], q2 = quat[2], q3 = quat[3];
        float nq = q0*q0 + q1*q1 + q2*q2 + q3*q3;
        float s = sqrtf(2.0f / nq);
        q0 *= s; q1 *= s; q2 *= s; q3 *= s;
        float E[16];
        E[0]  = 1.0f - q2*q2 - q3*q3; E[1]  = q1*q2 - q3*q0;        E[2]  = q1*q3 + q2*q0;        E[3]  = tran[0];
        E[4]  = q1*q2 + q3*q0;        E[5]  = 1.0f - q1*q1 - q3*q3; E[6]  = q2*q3 - q1*q0;        E[7]  = tran[1];
        E[8]  = q1*q3 - q2*q0;        E[9]  = q2*q3 + q1*q0;        E[10] = 1.0f - q1*q1 - q2*q2; E[11] = tran[2];
        E[12] = 0.0f; E[13] = 0.0f; E[14] = 0.0f; E[15] = 1.0f;

        float m[16], inv[16];
        #pragma unroll
        for (int i = 0; i < 16; i++) m[i] = view[i];

        inv[0]  =  m[5]*m[10]*m[15] - m[5]*m[11]*m[14] - m[9]*m[6]*m[15] + m[9]*m[7]*m[14] + m[13]*m[6]*m[11] - m[13]*m[7]*m[10];
        inv[4]  = -m[4]*m[10]*m[15] + m[4]*m[11]*m[14] + m[8]*m[6]*m[15] - m[8]*m[7]*m[14] - m[12]*m[6]*m[11] + m[12]*m[7]*m[10];
        inv[8]  =  m[4]*m[9]*m[15]  - m[4]*m[11]*m[13] - m[8]*m[5]*m[15] + m[8]*m[7]*m[13] + m[12]*m[5]*m[11] - m[12]*m[7]*m[9];
        inv[12] = -m[4]*m[9]*m[14]  + m[4]*m[10]*m[13] + m[8]*m[5]*m[14] - m[8]*m[6]*m[13] - m[12]*m[5]*m[10] + m[12]*m[6]*m[9];
        inv[1]  = -m[1]*m[10]*m[15] + m[1]*m[11]*m[14] + m[9]*m[2]*m[15] - m[9]*m[3]*m[14] - m[13]*m[2]*m[11] + m[13]*m[3]*m[10];
        inv[5]  =  m[0]*m[10]*m[15] - m[0]*m[11]*m[14] - m[8]*m[2]*m[15] + m[8]*m[3]*m[14] + m[12]*m[2]*m[11] - m[12]*m[3]*m[10];
        inv[9]  = -m[0]*m[9]*m[15]  + m[0]*m[11]*m[13] + m[8]*m[1]*m[15] - m[8]*m[3]*m[13] - m[12]*m[1]*m[11] + m[12]*m[3]*m[9];
        inv[13] =  m[0]*m[9]*m[14]  - m[0]*m[10]*m[13] - m[8]*m[1]*m[14] + m[8]*m[2]*m[13] + m[12]*m[1]*m[10] - m[12]*m[2]*m[9];
        inv[2]  =  m[1]*m[6]*m[15]  - m[1]*m[7]*m[14]  - m[5]*m[2]*m[15] + m[5]*m[3]*m[14] + m[13]*m[2]*m[7]  - m[13]*m[3]*m[6];
        inv[6]  = -m[0]*m[6]*m[15]  + m[0]*m[7]*m[14]  + m[4]*m[2]*m[15] - m[4]*m[3]*m[14] - m[12]*m[2]*m[7]  + m[12]*m[3]*m[6];
        inv[10] =  m[0]*m[5]*m[15]  - m[0]*m[7]*m[13]  - m[4]*m[1]*m[15] + m[4]*m[3]*m[13] + m[12]*m[1]*m[7]  - m[12]*m[3]*m[5];
        inv[14] = -m[0]*m[5]*m[14]  + m[0]*m[6]*m[13]  + m[4]*m[1]*m[14] - m[4]*m[2]*m[13] - m[12]*m[1]*m[6]  + m[12]*m[2]*m[5];
        inv[3]  = -m[1]*m[6]*m[11]  + m[1]*m[7]*m[10]  + m[5]*m[2]*m[11] - m[5]*m[3]*m[10] - m[9]*m[2]*m[7]   + m[9]*m[3]*m[6];
        inv[7]  =  m[0]*m[6]*m[11]  - m[0]*m[7]*m[10]  - m[4]*m[2]*m[11] + m[4]*m[3]*m[10] + m[8]*m[2]*m[7]   - m[8]*m[3]*m[6];
        inv[11] = -m[0]*m[5]*m[11]  + m[0]*m[7]*m[9]   + m[4]*m[1]*m[11] - m[4]*m[3]*m[9]  - m[8]*m[1]*m[7]   + m[8]*m[3]*m[5];
        inv[15] =  m[0]*m[5]*m[10]  - m[0]*m[6]*m[9]   - m[4]*m[1]*m[10] + m[4]*m[2]*m[9]  + m[8]*m[1]*m[6]   - m[8]*m[2]*m[5];

        float det = m[0]*inv[0] + m[1]*inv[4] + m[2]*inv[8] + m[3]*inv[12];
        float rdet = 1.0f / det;

        #pragma unroll
        for (int r = 0; r < 4; r++) {
            #pragma unroll
            for (int c = 0; c < 4; c++) {
                float a = 0.0f;
                #pragma unroll
                for (int k = 0; k < 4; k++) a += inv[4*r+k] * rdet * E[4*k+c];
                W[4*r+c] = a;
            }
        }
    }

    // ---- per-WAVE transform of the wave's own 128-point chunk into LDS ----
    // No block barrier (R1/R3/R4-proven exact): each wave reads only the sp range it
    // wrote, and DS ops are in-order within a wave. Waves overlap transform
    // (global-latency-bound) with other waves' main loop (LDS-bound).
    #pragma unroll
    for (int u = 0; u < CHUNK / 64; ++u) {
        int i = wave * CHUNK + u * 64 + lane;
        float x = model[3*i + 0];
        float y = model[3*i + 1];
        float z = model[3*i + 2];
        float X  = W[0]*x + W[1]*y + W[2]*z  + W[3];
        float Y  = W[4]*x + W[5]*y + W[6]*z  + W[7];
        float Z  = W[8]*x + W[9]*y + W[10]*z + W[11];
        float Wd = W[12]*x + W[13]*y + W[14]*z + W[15];
        float rw = 2.0f / Wd;                 // (1/w) * (1/RES)
        float px = X * rw, py = Y * rw, pz = Z * rw;
        float h  = 0.5f * (px*px + py*py + pz*pz);
        sp[i] = make_float4(px, py, pz, h);
    }

    // ---- main: wave's 128-pt chunk vs lane's 4 voxels; paired points -> v_min3 ----
    // t = h - c.p (d2 = |c|^2 + 2t, monotone); fmin order-independent -> exact.
    const float4* base = sp + wave * CHUNK;
    #pragma unroll 4
    for (int j = 0; j < CHUNK; j += 2) {
        float4 p0 = base[j];                 // wave-uniform addr -> LDS broadcast
        float4 p1 = base[j + 1];
        #pragma unroll
        for (int k = 0; k < VPT; k++) {
            float t0 = fmaf(nx[k], p0.x, fmaf(ny[k], p0.y, fmaf(nz[k], p0.z, p0.w)));
            float t1 = fmaf(nx[k], p1.x, fmaf(ny[k], p1.y, fmaf(nz[k], p1.z, p1.w)));
            mm[k] = fminf(mm[k], fminf(t0, t1));
        }
    }
    #pragma unroll
    for (int k = 0; k < VPT; k++)
        pmin[wave * VPB + lane * VPT + k] = mm[k];
    __syncthreads();

    // ---- epilogue: threads 0..255, thread t owns local voxel t ----
    if (tid < VPB) {
        const int g = blockIdx.x * VPB + tid;
        float m = 1e30f;
        #pragma unroll
        for (int c = 0; c < NWAVES; c++)
            m = fminf(m, pmin[c * VPB + tid]);
        float cx = centers[3*g + 0] * 2.0f;
        float cy = centers[3*g + 1] * 2.0f;
        float cz = centers[3*g + 2] * 2.0f;
        float c2 = cx*cx + cy*cy + cz*cz;
        float d2 = fmaf(2.0f, m, c2);
        float dmin = fminf(sqrtf(fmaxf(d2, 0.0f)), 0.25f);   // clamp at RES/2
        float occ  = fmaxf(1.0f - 4.0f * dmin, 0.0f);

        float mk = masks[g];
        float v0 = occ;
        float v1 = (freev[g] + occ_other[g]) * occ;
        float v2 = mk * occ;
        float v3 = mk;

        #pragma unroll
        for (int off = 32; off > 0; off >>= 1) {
            v0 += __shfl_down(v0, off);
            v1 += __shfl_down(v1, off);
            v2 += __shfl_down(v2, off);
            v3 += __shfl_down(v3, off);
        }
        if (lane == 0) {
            sred[wave*4 + 0] = v0;
            sred[wave*4 + 1] = v1;
            sred[wave*4 + 2] = v2;
            sred[wave*4 + 3] = v3;
        }
    }
    __syncthreads();
    if (tid < 4) {
        float s = sred[tid] + sred[4 + tid] + sred[8 + tid] + sred[12 + tid];
        partial[blockIdx.x * 4 + tid] = s;
    }
}

__global__ __launch_bounds__(256) void k_final(const float* __restrict__ partial,
                                               float* __restrict__ out) {
    __shared__ float sred[16];
    const int tid  = threadIdx.x;
    const int lane = tid & 63;
    const int wave = tid >> 6;

    float4 p = ((const float4*)partial)[tid];   // one block's 4 partials per thread
    float v0 = p.x, v1 = p.y, v2 = p.z, v3 = p.w;

    #pragma unroll
    for (int off = 32; off > 0; off >>= 1) {
        v0 += __shfl_down(v0, off);
        v1 += __shfl_down(v1, off);
        v2 += __shfl_down(v2, off);
        v3 += __shfl_down(v3, off);
    }
    if (lane == 0) {
        sred[wave*4 + 0] = v0;
        sred[wave*4 + 1] = v1;
        sred[wave*4 + 2] = v2;
        sred[wave*4 + 3] = v3;
    }
    __syncthreads();
    if (tid == 0) {
        float ps = sred[0] + sred[4] + sred[8]  + sred[12];
        float fo = sred[1] + sred[5] + sred[9]  + sred[13];
        float mo = sred[2] + sred[6] + sred[10] + sred[14];
        float ms = sred[3] + sred[7] + sred[11] + sred[15];
        float t1 = (ps > 0.0f) ? (fo / ps) : 0.0f;
        float t2 = (ms > 0.0f) ? (mo / ms) : 0.0f;
        out[0] = t1 - t2;
    }
}

extern "C" void kernel_launch(void* const* d_in, const int* in_sizes, int n_in,
                              void* d_out, int out_size, void* d_ws, size_t ws_size,
                              hipStream_t stream) {
    const float* quat      = (const float*)d_in[0];
    const float* tran      = (const float*)d_in[1];
    const float* model     = (const float*)d_in[2];
    const float* view      = (const float*)d_in[3];
    const float* centers   = (const float*)d_in[4];
    const float* freev     = (const float*)d_in[5];
    const float* occ_other = (const float*)d_in[6];
    const float* masks     = (const float*)d_in[7];
    float* out     = (float*)d_out;
    float* partial = (float*)d_ws;   // 1024 floats, fully overwritten by k_fused

    k_fused<<<NBLK, 1024, 0, stream>>>(quat, tran, model, view, centers, freev,
                                       occ_other, masks, partial);
    k_final<<<1, 256, 0, stream>>>(partial, out);
}

// Round 7
// 82.923 us; speedup vs baseline: 1.0860x; 1.0449x over previous
//
#include <hip/hip_runtime.h>
#include <math.h>

#define M_PTS   2048
#define N_VOX   65536
#define VPT     4                    // voxels per lane
#define VPB     256                  // voxels per block (64 lanes * VPT)
#define NBLK    (N_VOX / VPB)        // 256 blocks (1 per CU)
#define NWAVES  16                   // 1024-thread blocks
#define CHUNK   (M_PTS / NWAVES)     // 128 points per wave

// ws layout (floats): [0, 1024) per-block partials {pred_sum, fo_sum, mask_occ_sum, mask_sum} x 256
//
// Session record (R0-R6): this 2-dispatch stream-ordered structure is the measured
// optimum (83.6us). Probed and rejected: cooperative grid-sync (+98us: launch +
// device-fence tax), in-kernel flag/ticket sync (+4..9us: spin tail + L2
// writeback/cache-maintenance > one dispatch gap), 3-dispatch M-split (+4us: extra
// gap + cross-XCD intermediate re-read), barrier-drop + v_min3 pairing (within
// noise, never better). Kernel share ~15us of ~84us window; the rest is the
// harness's fixed 256MiB ws poison fill (~40us @ 83% HBM peak) + reset dispatches
// + ~4us/dispatch gap. Window noise band ~±3us (fill dur varies 39.3-41.6us).

__global__ __launch_bounds__(1024) void k_fused(const float* __restrict__ quat,
                                                const float* __restrict__ tran,
                                                const float* __restrict__ model,
                                                const float* __restrict__ view,
                                                const float* __restrict__ centers,
                                                const float* __restrict__ freev,
                                                const float* __restrict__ occ_other,
                                                const float* __restrict__ masks,
                                                float* __restrict__ partial) {
    __shared__ float4 sp[M_PTS];             // (x,y,z)/RES, h = 0.5*|p/RES|^2  -> 32 KB
    __shared__ float  pmin[NWAVES * VPB];    // [chunk][local voxel]            -> 16 KB
    __shared__ float  sred[16];              // cross-wave sum combine

    const int tid = threadIdx.x;

    // ---- per-block uniform prep: W = inv(view) * quat_matrix (redundant on all threads) ----
    float W[16];
    {
        float q0 = quat[0], q1 = quat[1], q2 = quat[2], q3 = quat[3];
        float nq = q0*q0 + q1*q1 + q2*q2 + q3*q3;
        float s = sqrtf(2.0f / nq);
        q0 *= s; q1 *= s; q2 *= s; q3 *= s;
        float E[16];
        E[0]  = 1.0f - q2*q2 - q3*q3; E[1]  = q1*q2 - q3*q0;        E[2]  = q1*q3 + q2*q0;        E[3]  = tran[0];
        E[4]  = q1*q2 + q3*q0;        E[5]  = 1.0f - q1*q1 - q3*q3; E[6]  = q2*q3 - q1*q0;        E[7]  = tran[1];
        E[8]  = q1*q3 - q2*q0;        E[9]  = q2*q3 + q1*q0;        E[10] = 1.0f - q1*q1 - q2*q2; E[11] = tran[2];
        E[12] = 0.0f; E[13] = 0.0f; E[14] = 0.0f; E[15] = 1.0f;

        float m[16], inv[16];
        #pragma unroll
        for (int i = 0; i < 16; i++) m[i] = view[i];

        inv[0]  =  m[5]*m[10]*m[15] - m[5]*m[11]*m[14] - m[9]*m[6]*m[15] + m[9]*m[7]*m[14] + m[13]*m[6]*m[11] - m[13]*m[7]*m[10];
        inv[4]  = -m[4]*m[10]*m[15] + m[4]*m[11]*m[14] + m[8]*m[6]*m[15] - m[8]*m[7]*m[14] - m[12]*m[6]*m[11] + m[12]*m[7]*m[10];
        inv[8]  =  m[4]*m[9]*m[15]  - m[4]*m[11]*m[13] - m[8]*m[5]*m[15] + m[8]*m[7]*m[13] + m[12]*m[5]*m[11] - m[12]*m[7]*m[9];
        inv[12] = -m[4]*m[9]*m[14]  + m[4]*m[10]*m[13] + m[8]*m[5]*m[14] - m[8]*m[6]*m[13] - m[12]*m[5]*m[10] + m[12]*m[6]*m[9];
        inv[1]  = -m[1]*m[10]*m[15] + m[1]*m[11]*m[14] + m[9]*m[2]*m[15] - m[9]*m[3]*m[14] - m[13]*m[2]*m[11] + m[13]*m[3]*m[10];
        inv[5]  =  m[0]*m[10]*m[15] - m[0]*m[11]*m[14] - m[8]*m[2]*m[15] + m[8]*m[3]*m[14] + m[12]*m[2]*m[11] - m[12]*m[3]*m[10];
        inv[9]  = -m[0]*m[9]*m[15]  + m[0]*m[11]*m[13] + m[8]*m[1]*m[15] - m[8]*m[3]*m[13] - m[12]*m[1]*m[11] + m[12]*m[3]*m[9];
        inv[13] =  m[0]*m[9]*m[14]  - m[0]*m[10]*m[13] - m[8]*m[1]*m[14] + m[8]*m[2]*m[13] + m[12]*m[1]*m[10] - m[12]*m[2]*m[9];
        inv[2]  =  m[1]*m[6]*m[15]  - m[1]*m[7]*m[14]  - m[5]*m[2]*m[15] + m[5]*m[3]*m[14] + m[13]*m[2]*m[7]  - m[13]*m[3]*m[6];
        inv[6]  = -m[0]*m[6]*m[15]  + m[0]*m[7]*m[14]  + m[4]*m[2]*m[15] - m[4]*m[3]*m[14] - m[12]*m[2]*m[7]  + m[12]*m[3]*m[6];
        inv[10] =  m[0]*m[5]*m[15]  - m[0]*m[7]*m[13]  - m[4]*m[1]*m[15] + m[4]*m[3]*m[13] + m[12]*m[1]*m[7]  - m[12]*m[3]*m[5];
        inv[14] = -m[0]*m[5]*m[14]  + m[0]*m[6]*m[13]  + m[4]*m[1]*m[14] - m[4]*m[2]*m[13] - m[12]*m[1]*m[6]  + m[12]*m[2]*m[5];
        inv[3]  = -m[1]*m[6]*m[11]  + m[1]*m[7]*m[10]  + m[5]*m[2]*m[11] - m[5]*m[3]*m[10] - m[9]*m[2]*m[7]   + m[9]*m[3]*m[6];
        inv[7]  =  m[0]*m[6]*m[11]  - m[0]*m[7]*m[10]  - m[4]*m[2]*m[11] + m[4]*m[3]*m[10] + m[8]*m[2]*m[7]   - m[8]*m[3]*m[6];
        inv[11] = -m[0]*m[5]*m[11]  + m[0]*m[7]*m[9]   + m[4]*m[1]*m[11] - m[4]*m[3]*m[9]  - m[8]*m[1]*m[7]   + m[8]*m[3]*m[5];
        inv[15] =  m[0]*m[5]*m[10]  - m[0]*m[6]*m[9]   - m[4]*m[1]*m[10] + m[4]*m[2]*m[9]  + m[8]*m[1]*m[6]   - m[8]*m[2]*m[5];

        float det = m[0]*inv[0] + m[1]*inv[4] + m[2]*inv[8] + m[3]*inv[12];
        float rdet = 1.0f / det;

        #pragma unroll
        for (int r = 0; r < 4; r++) {
            #pragma unroll
            for (int c = 0; c < 4; c++) {
                float a = 0.0f;
                #pragma unroll
                for (int k = 0; k < 4; k++) a += inv[4*r+k] * rdet * E[4*k+c];
                W[4*r+c] = a;
            }
        }
    }

    // ---- transform model points into LDS: p/RES and h = 0.5*|p/RES|^2 (2 pts/thread) ----
    #pragma unroll
    for (int i = tid; i < M_PTS; i += 1024) {
        float x = model[3*i + 0];
        float y = model[3*i + 1];
        float z = model[3*i + 2];
        float X  = W[0]*x + W[1]*y + W[2]*z  + W[3];
        float Y  = W[4]*x + W[5]*y + W[6]*z  + W[7];
        float Z  = W[8]*x + W[9]*y + W[10]*z + W[11];
        float Wd = W[12]*x + W[13]*y + W[14]*z + W[15];
        float rw = 2.0f / Wd;                 // (1/w) * (1/RES)
        float px = X * rw, py = Y * rw, pz = Z * rw;
        float h  = 0.5f * (px*px + py*py + pz*pz);
        sp[i] = make_float4(px, py, pz, h);
    }
    __syncthreads();

    // ---- main: 16 waves x (128-pt chunk); lane covers 4 voxels ----
    const int lane = tid & 63;
    const int wave = tid >> 6;
    const int vbase = blockIdx.x * VPB + lane * VPT;

    float nx[VPT], ny[VPT], nz[VPT], mm[VPT];
    #pragma unroll
    for (int k = 0; k < VPT; k++) {
        int g = vbase + k;
        nx[k] = -centers[3*g + 0] * 2.0f;   // -(c/RES)
        ny[k] = -centers[3*g + 1] * 2.0f;
        nz[k] = -centers[3*g + 2] * 2.0f;
        mm[k] = 1e30f;
    }

    const float4* base = sp + wave * CHUNK;
    #pragma unroll 4
    for (int j = 0; j < CHUNK; ++j) {
        float4 p = base[j];                 // wave-uniform addr -> LDS broadcast
        // t = h - c.p  (d2 = |c|^2 + 2t, monotone)
        #pragma unroll
        for (int k = 0; k < VPT; k++)
            mm[k] = fminf(mm[k], fmaf(nx[k], p.x, fmaf(ny[k], p.y, fmaf(nz[k], p.z, p.w))));
    }
    #pragma unroll
    for (int k = 0; k < VPT; k++)
        pmin[wave * VPB + lane * VPT + k] = mm[k];
    __syncthreads();

    // ---- epilogue: threads 0..255, thread t owns local voxel t ----
    if (tid < VPB) {
        const int g = blockIdx.x * VPB + tid;
        float m = 1e30f;
        #pragma unroll
        for (int c = 0; c < NWAVES; c++)
            m = fminf(m, pmin[c * VPB + tid]);
        float cx = centers[3*g + 0] * 2.0f;
        float cy = centers[3*g + 1] * 2.0f;
        float cz = centers[3*g + 2] * 2.0f;
        float c2 = cx*cx + cy*cy + cz*cz;
        float d2 = fmaf(2.0f, m, c2);
        float dmin = fminf(sqrtf(fmaxf(d2, 0.0f)), 0.25f);   // clamp at RES/2
        float occ  = fmaxf(1.0f - 4.0f * dmin, 0.0f);

        float mk = masks[g];
        float v0 = occ;
        float v1 = (freev[g] + occ_other[g]) * occ;
        float v2 = mk * occ;
        float v3 = mk;

        #pragma unroll
        for (int off = 32; off > 0; off >>= 1) {
            v0 += __shfl_down(v0, off);
            v1 += __shfl_down(v1, off);
            v2 += __shfl_down(v2, off);
            v3 += __shfl_down(v3, off);
        }
        if (lane == 0) {
            sred[wave*4 + 0] = v0;
            sred[wave*4 + 1] = v1;
            sred[wave*4 + 2] = v2;
            sred[wave*4 + 3] = v3;
        }
    }
    __syncthreads();
    if (tid < 4) {
        float s = sred[tid] + sred[4 + tid] + sred[8 + tid] + sred[12 + tid];
        partial[blockIdx.x * 4 + tid] = s;
    }
}

__global__ __launch_bounds__(256) void k_final(const float* __restrict__ partial,
                                               float* __restrict__ out) {
    __shared__ float sred[16];
    const int tid  = threadIdx.x;
    const int lane = tid & 63;
    const int wave = tid >> 6;

    float4 p = ((const float4*)partial)[tid];   // one block's 4 partials per thread
    float v0 = p.x, v1 = p.y, v2 = p.z, v3 = p.w;

    #pragma unroll
    for (int off = 32; off > 0; off >>= 1) {
        v0 += __shfl_down(v0, off);
        v1 += __shfl_down(v1, off);
        v2 += __shfl_down(v2, off);
        v3 += __shfl_down(v3, off);
    }
    if (lane == 0) {
        sred[wave*4 + 0] = v0;
        sred[wave*4 + 1] = v1;
        sred[wave*4 + 2] = v2;
        sred[wave*4 + 3] = v3;
    }
    __syncthreads();
    if (tid == 0) {
        float ps = sred[0] + sred[4] + sred[8]  + sred[12];
        float fo = sred[1] + sred[5] + sred[9]  + sred[13];
        float mo = sred[2] + sred[6] + sred[10] + sred[14];
        float ms = sred[3] + sred[7] + sred[11] + sred[15];
        float t1 = (ps > 0.0f) ? (fo / ps) : 0.0f;
        float t2 = (ms > 0.0f) ? (mo / ms) : 0.0f;
        out[0] = t1 - t2;
    }
}

extern "C" void kernel_launch(void* const* d_in, const int* in_sizes, int n_in,
                              void* d_out, int out_size, void* d_ws, size_t ws_size,
                              hipStream_t stream) {
    const float* quat      = (const float*)d_in[0];
    const float* tran      = (const float*)d_in[1];
    const float* model     = (const float*)d_in[2];
    const float* view      = (const float*)d_in[3];
    const float* centers   = (const float*)d_in[4];
    const float* freev     = (const float*)d_in[5];
    const float* occ_other = (const float*)d_in[6];
    const float* masks     = (const float*)d_in[7];
    float* out     = (float*)d_out;
    float* partial = (float*)d_ws;   // 1024 floats, fully overwritten by k_fused

    k_fused<<<NBLK, 1024, 0, stream>>>(quat, tran, model, view, centers, freev,
                                       occ_other, masks, partial);
    k_final<<<1, 256, 0, stream>>>(partial, out);
}